// Round 18
// baseline (457.755 us; speedup 1.0000x reference)
//
#include <hip/hip_runtime.h>
#include <hip/hip_bf16.h>

#define NEGINF -1e30f

typedef __attribute__((ext_vector_type(8))) short short8;
typedef __attribute__((ext_vector_type(4))) float f32x4;
typedef __attribute__((ext_vector_type(4))) int int4_t;

// Clamp-free: IEEE inf semantics give exact limits (exp->inf => rcp->0), NaN-free.
__device__ __forceinline__ float fast_sigmoid(float x) {
    return __builtin_amdgcn_rcpf(1.f + __expf(-x));
}
__device__ __forceinline__ float fast_tanh(float x) {
    return 1.f - 2.f * __builtin_amdgcn_rcpf(1.f + __expf(2.f * x));
}
// round-to-nearest-even f32 -> bf16 bits
__device__ __forceinline__ short f2bf(float f) {
    unsigned u = __float_as_uint(f);
    return (short)((u + 0x7fff + ((u >> 16) & 1)) >> 16);
}
__device__ __forceinline__ float bf2f(short b) {
    return __uint_as_float(((unsigned)(unsigned short)b) << 16);
}

// LDS-only workgroup barrier (proven R3-R17): waits lgkmcnt only; in-flight global
// loads/stores are NOT drained. Safe when all cross-thread traffic goes through LDS.
__device__ __forceinline__ void bar_lds() {
    asm volatile("s_waitcnt lgkmcnt(0)\n\ts_barrier" ::: "memory");
}

// ---------------- MFMA GEMM (R12, known-good): out = A @ W^T + bias ------------------
__global__ __launch_bounds__(256) void gemm_bias(
    const float* __restrict__ A,
    const float* __restrict__ W1, const float* __restrict__ b1, float* __restrict__ out1,
    const float* __restrict__ W2, const float* __restrict__ b2, float* __restrict__ out2,
    const int* __restrict__ lengths,
    int M, int N, int K, int nsplit, int mode) {
    const int m0 = blockIdx.y * 64;
    if ((m0 & 511) >= lengths[m0 >> 9]) return;  // uniform per block; rows unread
    __shared__ __align__(16) short Abh[2][2048];
    __shared__ __align__(16) short Abl[2][2048];
    __shared__ __align__(16) short Bbh[2][2048];
    __shared__ __align__(16) short Bbl[2][2048];
    const int tid = threadIdx.x;
    int bx = blockIdx.x;
    const float* W = W1; const float* bias = b1; float* out = out1;
    int n0;
    if (bx < nsplit) {
        n0 = bx * 64;
    } else {
        W = W2; bias = b2; out = out2;
        n0 = (bx - nsplit) * 64;
    }
    const int wave = tid >> 6;
    const int lane = tid & 63;
    const int mrow = lane & 15;
    const int quad = lane >> 4;
    const int wm = (wave >> 1) * 32;
    const int wn = (wave & 1) * 32;

    const int r_ = tid >> 2;
    const int sg = (tid & 3) * 8;

    f32x4 acc[2][2];
#pragma unroll
    for (int mt = 0; mt < 2; mt++)
#pragma unroll
        for (int nt = 0; nt < 2; nt++) acc[mt][nt] = (f32x4){0.f, 0.f, 0.f, 0.f};

    float4 a0 = *(const float4*)(A + (size_t)(m0 + r_) * K + sg);
    float4 a1 = *(const float4*)(A + (size_t)(m0 + r_) * K + sg + 4);
    float4 w0 = *(const float4*)(W + (size_t)(n0 + r_) * K + sg);
    float4 w1 = *(const float4*)(W + (size_t)(n0 + r_) * K + sg + 4);

    for (int k0 = 0; k0 < K; k0 += 32) {
        const int cur = (k0 >> 5) & 1;
        {
            float av[8] = {a0.x, a0.y, a0.z, a0.w, a1.x, a1.y, a1.z, a1.w};
            float wv[8] = {w0.x, w0.y, w0.z, w0.w, w1.x, w1.y, w1.z, w1.w};
            short8 ah, al, bh, bl;
#pragma unroll
            for (int j = 0; j < 8; j++) {
                short h = f2bf(av[j]); ah[j] = h; al[j] = f2bf(av[j] - bf2f(h));
                short g = f2bf(wv[j]); bh[j] = g; bl[j] = f2bf(wv[j] - bf2f(g));
            }
            *(short8*)&Abh[cur][r_ * 32 + sg] = ah;
            *(short8*)&Abl[cur][r_ * 32 + sg] = al;
            *(short8*)&Bbh[cur][r_ * 32 + sg] = bh;
            *(short8*)&Bbl[cur][r_ * 32 + sg] = bl;
        }
        if (k0 + 32 < K) {
            a0 = *(const float4*)(A + (size_t)(m0 + r_) * K + k0 + 32 + sg);
            a1 = *(const float4*)(A + (size_t)(m0 + r_) * K + k0 + 32 + sg + 4);
            w0 = *(const float4*)(W + (size_t)(n0 + r_) * K + k0 + 32 + sg);
            w1 = *(const float4*)(W + (size_t)(n0 + r_) * K + k0 + 32 + sg + 4);
        }
        bar_lds();
        short8 Ah[2], Al[2], Bh[2], Bl[2];
#pragma unroll
        for (int t = 0; t < 2; t++) {
            int ar = (wm + t * 16 + mrow) * 32 + quad * 8;
            int br = (wn + t * 16 + mrow) * 32 + quad * 8;
            Ah[t] = *(const short8*)&Abh[cur][ar];
            Al[t] = *(const short8*)&Abl[cur][ar];
            Bh[t] = *(const short8*)&Bbh[cur][br];
            Bl[t] = *(const short8*)&Bbl[cur][br];
        }
#pragma unroll
        for (int mt = 0; mt < 2; mt++)
#pragma unroll
            for (int nt = 0; nt < 2; nt++) {
                acc[mt][nt] = __builtin_amdgcn_mfma_f32_16x16x32_bf16(Ah[mt], Bh[nt], acc[mt][nt], 0, 0, 0);
                acc[mt][nt] = __builtin_amdgcn_mfma_f32_16x16x32_bf16(Al[mt], Bh[nt], acc[mt][nt], 0, 0, 0);
                acc[mt][nt] = __builtin_amdgcn_mfma_f32_16x16x32_bf16(Ah[mt], Bl[nt], acc[mt][nt], 0, 0, 0);
            }
        bar_lds();
    }
    float bsv[2];
#pragma unroll
    for (int nt = 0; nt < 2; nt++) bsv[nt] = bias[n0 + wn + nt * 16 + mrow];
#pragma unroll
    for (int mt = 0; mt < 2; mt++)
#pragma unroll
        for (int nt = 0; nt < 2; nt++) {
            int n = n0 + wn + nt * 16 + mrow;
#pragma unroll
            for (int r = 0; r < 4; r++) {
                int m = m0 + wm + mt * 16 + quad * 4 + r;
                float val = acc[mt][nt][r] + bsv[nt];
                if (mode == 1) val = fast_sigmoid(val) * A[(size_t)m * K + n];
                out[(size_t)m * N + n] = val;
            }
        }
}

// ---------------- Attention, 8 queries per block (R12, known-good) -------------------
__global__ __launch_bounds__(512) void attn_kernel(
    const float* __restrict__ v, const int* __restrict__ lengths,
    const float* __restrict__ own, const float* __restrict__ comp,
    const float* __restrict__ v_attn, float* __restrict__ inp) {
    const int L = 512, D = 256, H = 128;
    const int b = blockIdx.x >> 6;
    const int q0 = (blockIdx.x & 63) * 8;
    const int len = lengths[b];
    if (q0 >= len) return;
    const int tid = threadIdx.x;
    const float K2E = 2.8853900817779268f;  // 2*log2(e)
    __shared__ __align__(16) float oKT[128 * 8];
    __shared__ float va2s[128];
    __shared__ __align__(16) float scf[512 * 12];
    __shared__ float inv8[8];

    for (int i = tid; i < 1024; i += 512) {
        int qq = i >> 7, hh = i & 127;
        oKT[hh * 8 + qq] = K2E * own[((size_t)(b * L + q0 + qq)) * H + hh];
    }
    if (tid < 128) va2s[tid] = -2.f * v_attn[tid];
    __syncthreads();

    {
        const int k = tid;
        float acc[8];
#pragma unroll
        for (int q = 0; q < 8; q++) acc[q] = 0.f;
        if (k < len) {
            const float* cp = comp + ((size_t)(b * L + k)) * H;
            for (int h = 0; h < 128; h += 4) {
                float4 c4 = *(const float4*)(cp + h);
                const float* cv = (const float*)&c4;
#pragma unroll
                for (int j = 0; j < 4; j++) {
                    float cK = cv[j] * K2E;
                    float va = va2s[h + j];
                    float4 o0 = *(const float4*)&oKT[(h + j) * 8];
                    float4 o1 = *(const float4*)&oKT[(h + j) * 8 + 4];
                    const float* op0 = (const float*)&o0;
                    const float* op1 = (const float*)&o1;
#pragma unroll
                    for (int q = 0; q < 4; q++) {
                        float r = __builtin_amdgcn_rcpf(1.f + exp2f(cK + op0[q]));
                        acc[q] = fmaf(va, r, acc[q]);
                    }
#pragma unroll
                    for (int q = 0; q < 4; q++) {
                        float r = __builtin_amdgcn_rcpf(1.f + exp2f(cK + op1[q]));
                        acc[4 + q] = fmaf(va, r, acc[4 + q]);
                    }
                }
            }
#pragma unroll
            for (int q = 0; q < 8; q++) acc[q] = __expf(acc[q]);  // bounded, no max pass
        }
        *(float4*)&scf[k * 12] = *(float4*)&acc[0];
        *(float4*)&scf[k * 12 + 4] = *(float4*)&acc[4];
    }
    __syncthreads();

    {
        int w = tid >> 6, l = tid & 63;
        float s = 0.f;
#pragma unroll
        for (int kk = 0; kk < 8; kk++) s += scf[(l + kk * 64) * 12 + w];
#pragma unroll
        for (int off = 1; off < 64; off <<= 1) s += __shfl_xor(s, off);
        if (l == 0) inv8[w] = __builtin_amdgcn_rcpf(s);
    }
    __syncthreads();

    {
        const int d = tid & 255;
        const int qh = tid >> 8;
        float c0 = 0.f, c1 = 0.f, c2 = 0.f, c3 = 0.f;
        const float* vb = v + ((size_t)b * L) * D + d;
        for (int k = 0; k < L; k += 2) {
            float v0 = vb[(size_t)k * D];
            float v1 = vb[(size_t)(k + 1) * D];
            float4 s0 = *(const float4*)&scf[k * 12 + qh * 4];
            float4 s1 = *(const float4*)&scf[(k + 1) * 12 + qh * 4];
            c0 += s0.x * v0 + s1.x * v1;
            c1 += s0.y * v0 + s1.y * v1;
            c2 += s0.z * v0 + s1.z * v1;
            c3 += s0.w * v0 + s1.w * v1;
        }
        float cc[4] = {c0, c1, c2, c3};
#pragma unroll
        for (int j = 0; j < 4; j++) {
            int q = q0 + qh * 4 + j;
            size_t row = ((size_t)(b * L + q)) * 512;
            inp[row + 256 + d] = cc[j] * inv8[qh * 4 + j];
            inp[row + d] = v[((size_t)(b * L + q)) * D + d];
        }
    }
}

// ---------------- GRU recurrence: DUAL-SEQUENCE (f+b same batch, one block) ----------
// One block per batch (4 blocks), 512 threads = 8 waves. Both directions share len ->
// identical chunk/barrier structure; each step-loop iteration advances BOTH
// recurrences: 12 i8 MFMAs/wave (6 per dir), two independent gate chains (ILP).
// The serial skeleton (af-read latency, barrier, loop bookkeeping) is paid once per
// TWO steps. i8 scheme as R17 (Q0.13 h hi/lo rows, per-row-scaled i8 W, exact i32).
// hbufc[dir][parity]: hi at byte 0, lo at byte 192 (disjoint bank halves).
// Chunk = 8 steps to keep xp register arrays at 96 floats.
__global__ __launch_bounds__(512, 1) void gru_kernel(
    const float* __restrict__ xp_f, const float* __restrict__ xp_b,
    const float* __restrict__ w_hh_f, const float* __restrict__ w_hh_b,
    const float* __restrict__ b_hh_f, const float* __restrict__ b_hh_b,
    const int* __restrict__ lengths, float* __restrict__ out) {
    const int L = 512, H = 128;
    const int b = blockIdx.x;  // 0..3
    const int tid = threadIdx.x;
    const int wave = tid >> 6;
    const int lane = tid & 63;
    const int mrow = lane & 15;
    const int quad = lane >> 4;
    const int jj = 16 * wave + lane;  // gate dim for lanes lane<16

    // [dir][parity][ h_hi bytes 0..127 | pad | h_lo bytes 192..319 | pad..383 ]
    __shared__ __align__(16) signed char hbufc[2][2][384];

    // ---- W_hh -> per-row i8 + scale, both dirs ----
    int4_t wb[2][3][2];
    float ws[2][3];
#pragma unroll
    for (int d = 0; d < 2; d++) {
        const float* w_hh = d ? w_hh_b : w_hh_f;
#pragma unroll
        for (int g = 0; g < 3; g++) {
            int row = g * 128 + 16 * wave + mrow;
            float wv[32];
#pragma unroll
            for (int kt = 0; kt < 2; kt++)
#pragma unroll
                for (int j4 = 0; j4 < 4; j4++) {
                    float4 f4 = *(const float4*)(w_hh + (size_t)row * H + kt * 64 + quad * 16 + j4 * 4);
                    wv[kt * 16 + j4 * 4 + 0] = f4.x;
                    wv[kt * 16 + j4 * 4 + 1] = f4.y;
                    wv[kt * 16 + j4 * 4 + 2] = f4.z;
                    wv[kt * 16 + j4 * 4 + 3] = f4.w;
                }
            float mx = 0.f;
#pragma unroll
            for (int j = 0; j < 32; j++) mx = fmaxf(mx, fabsf(wv[j]));
            mx = fmaxf(mx, __shfl_xor(mx, 16));
            mx = fmaxf(mx, __shfl_xor(mx, 32));
            mx = fmaxf(mx, 1e-30f);
            float inv_s = 127.f / mx;
            ws[d][g] = (mx / 127.f) * (1.f / 8192.f);
#pragma unroll
            for (int kt = 0; kt < 2; kt++) {
                int tmp[4] = {0, 0, 0, 0};
#pragma unroll
                for (int j = 0; j < 16; j++) {
                    int q = (int)rintf(wv[kt * 16 + j] * inv_s);
                    tmp[j >> 2] |= (q & 0xff) << ((j & 3) * 8);
                }
                wb[d][g][kt] = (int4_t){tmp[0], tmp[1], tmp[2], tmp[3]};
            }
        }
    }
    float br[2], bz[2], bn[2], hcur[2];
    hcur[0] = hcur[1] = 0.f;
    if (lane < 16) {
#pragma unroll
        for (int d = 0; d < 2; d++) {
            const float* b_hh = d ? b_hh_b : b_hh_f;
            br[d] = b_hh[jj];
            bz[d] = b_hh[128 + jj];
            bn[d] = b_hh[256 + jj];
        }
    }

    const int len = lengths[b];
    // pre-zero masked tail rows (both dirs: whole 256-wide row)
    for (int i = tid; i < (L - len) * 256; i += 512) {
        int tt = len + (i >> 8);
        int kk = i & 255;
        out[((size_t)(b * L + tt)) * 256 + kk] = 0.f;
    }
    for (int i = tid; i < 1536; i += 512) ((signed char*)hbufc)[i] = 0;

    const int nch = (len + 7) >> 3;  // 8-step chunks; len >= 256 so chunk 0 full
    // gate-lane xp registers, both dirs, current chunk
    float xf0[8], xf1[8], xf2[8], xb0[8], xb1[8], xb2[8];
    if (lane < 16) {
#pragma unroll
        for (int s = 0; s < 8; s++) {
            if (s < len) {
                size_t bf = ((size_t)(b * L + s)) * 384;
                size_t bb = ((size_t)(b * L + (len - 1 - s))) * 384;
                xf0[s] = xp_f[bf + jj]; xf1[s] = xp_f[bf + 128 + jj]; xf2[s] = xp_f[bf + 256 + jj];
                xb0[s] = xp_b[bb + jj]; xb1[s] = xp_b[bb + 128 + jj]; xb2[s] = xp_b[bb + 256 + jj];
            }
        }
    }
    __syncthreads();

    const int bbase = ((mrow & 1) ? 192 : 0) + quad * 16;  // A-frag: row0=hi, row1=lo
    int par = 0;

    for (int c = 0; c < nch; c++) {
        const int cnt = min(8, len - c * 8);
        // prefetch chunk c+1 (both dirs) into second register sets
        float nf0[8], nf1[8], nf2[8], nb0[8], nb1[8], nb2[8];
        if (lane < 16 && c + 1 < nch) {
#pragma unroll
            for (int s = 0; s < 8; s++) {
                int rr = (c + 1) * 8 + s;
                if (rr < len) {
                    size_t bf = ((size_t)(b * L + rr)) * 384;
                    size_t bb = ((size_t)(b * L + (len - 1 - rr))) * 384;
                    nf0[s] = xp_f[bf + jj]; nf1[s] = xp_f[bf + 128 + jj]; nf2[s] = xp_f[bf + 256 + jj];
                    nb0[s] = xp_b[bb + jj]; nb1[s] = xp_b[bb + 128 + jj]; nb2[s] = xp_b[bb + 256 + jj];
                }
            }
        }
#pragma unroll
        for (int s = 0; s < 8; s++) {
            if (s < cnt) {  // cnt uniform per block -> barrier counts match
                int4_t aff0 = *(const int4_t*)&hbufc[0][par][bbase];
                int4_t aff1 = *(const int4_t*)&hbufc[0][par][bbase + 64];
                int4_t afb0 = *(const int4_t*)&hbufc[1][par][bbase];
                int4_t afb1 = *(const int4_t*)&hbufc[1][par][bbase + 64];
                int4_t a[2][3];
#pragma unroll
                for (int d = 0; d < 2; d++)
#pragma unroll
                    for (int g = 0; g < 3; g++) a[d][g] = (int4_t){0, 0, 0, 0};
                // g-major, dirs interleaved: r-accs complete first for both chains
#pragma unroll
                for (int g = 0; g < 3; g++) {
                    a[0][g] = __builtin_amdgcn_mfma_i32_16x16x64_i8(aff0, wb[0][g][0], a[0][g], 0, 0, 0);
                    a[0][g] = __builtin_amdgcn_mfma_i32_16x16x64_i8(aff1, wb[0][g][1], a[0][g], 0, 0, 0);
                    a[1][g] = __builtin_amdgcn_mfma_i32_16x16x64_i8(afb0, wb[1][g][0], a[1][g], 0, 0, 0);
                    a[1][g] = __builtin_amdgcn_mfma_i32_16x16x64_i8(afb1, wb[1][g][1], a[1][g], 0, 0, 0);
                }
                if (lane < 16) {
                    // forward gate chain
                    float rf = fast_sigmoid(fmaf((float)(a[0][0][0] * 64 + a[0][0][1]), ws[0][0], xf0[s] + br[0]));
                    float zf = fast_sigmoid(fmaf((float)(a[0][1][0] * 64 + a[0][1][1]), ws[0][1], xf1[s] + bz[0]));
                    float hhf = fmaf((float)(a[0][2][0] * 64 + a[0][2][1]), ws[0][2], bn[0]);
                    // backward gate chain (independent -> ILP with forward)
                    float rb = fast_sigmoid(fmaf((float)(a[1][0][0] * 64 + a[1][0][1]), ws[1][0], xb0[s] + br[1]));
                    float zb = fast_sigmoid(fmaf((float)(a[1][1][0] * 64 + a[1][1][1]), ws[1][1], xb1[s] + bz[1]));
                    float hhb = fmaf((float)(a[1][2][0] * 64 + a[1][2][1]), ws[1][2], bn[1]);
                    float nf = fast_tanh(xf2[s] + rf * hhf);
                    float nb = fast_tanh(xb2[s] + rb * hhb);
                    float hnf = (1.f - zf) * nf + zf * hcur[0];
                    float hnb = (1.f - zb) * nb + zb * hcur[1];
                    hcur[0] = hnf;
                    hcur[1] = hnb;
                    // quantize h -> Q0.13 hi/lo (|h| < 1)
                    float hsf = fminf(fmaxf(hnf * 8192.f, -8191.f), 8191.f);
                    float hsb = fminf(fmaxf(hnb * 8192.f, -8191.f), 8191.f);
                    int h13f = (int)rintf(hsf);
                    int h13b = (int)rintf(hsb);
                    int hif = h13f >> 6, lof = h13f - (hif << 6);
                    int hib = h13b >> 6, lob = h13b - (hib << 6);
                    hbufc[0][par ^ 1][jj] = (signed char)hif;
                    hbufc[0][par ^ 1][192 + jj] = (signed char)lof;
                    hbufc[1][par ^ 1][jj] = (signed char)hib;
                    hbufc[1][par ^ 1][192 + jj] = (signed char)lob;
                    int t = c * 8 + s;
                    out[((size_t)(b * L + t)) * 256 + jj] = hnf;                  // dir 0
                    out[((size_t)(b * L + (len - 1 - t))) * 256 + 128 + jj] = hnb; // dir 1
                }
                par ^= 1;
                bar_lds();  // hbufc[.][par] ready; ONE barrier advances BOTH sequences
            }
        }
        // rotate prefetched chunk into place (vmcnt wait lands here, a full chunk later)
        if (lane < 16 && c + 1 < nch) {
#pragma unroll
            for (int s = 0; s < 8; s++) {
                xf0[s] = nf0[s]; xf1[s] = nf1[s]; xf2[s] = nf2[s];
                xb0[s] = nb0[s]; xb1[s] = nb1[s]; xb2[s] = nb2[s];
            }
        }
    }
}

extern "C" void kernel_launch(void* const* d_in, const int* in_sizes, int n_in,
                              void* d_out, int out_size, void* d_ws, size_t ws_size,
                              hipStream_t stream) {
    const int B = 4, L = 512, D = 256, H = 128;
    const int M = B * L;  // 2048

    const float* v      = (const float*)d_in[0];
    const int* lengths  = (const int*)d_in[1];
    const float* own_W  = (const float*)d_in[3];
    const float* own_b  = (const float*)d_in[4];
    const float* comp_W = (const float*)d_in[5];
    const float* comp_b = (const float*)d_in[6];
    const float* v_attn = (const float*)d_in[7];
    const float* gate_W = (const float*)d_in[8];
    const float* gate_b = (const float*)d_in[9];
    const float* w_ih_f = (const float*)d_in[10];
    const float* w_hh_f = (const float*)d_in[11];
    const float* b_ih_f = (const float*)d_in[12];
    const float* b_hh_f = (const float*)d_in[13];
    const float* w_ih_b = (const float*)d_in[14];
    const float* w_hh_b = (const float*)d_in[15];
    const float* b_ih_b = (const float*)d_in[16];
    const float* b_hh_b = (const float*)d_in[17];

    float* ws   = (float*)d_ws;
    float* own  = ws;                       // [2048,128]
    float* comp = own + (size_t)M * H;      // [2048,128]
    float* inp  = comp + (size_t)M * H;     // [2048,512]
    float* gated = inp + (size_t)M * 512;   // [2048,512]
    float* xp_f = gated + (size_t)M * 512;  // [2048,384]
    float* xp_b = xp_f + (size_t)M * 384;   // [2048,384]
    float* out  = (float*)d_out;            // [2048,256]

    // 1: own & comp projections in one launch (tiles 0..1 -> own, 2..3 -> comp)
    gemm_bias<<<dim3(4, M / 64), 256, 0, stream>>>(
        v, own_W, own_b, own, comp_W, comp_b, comp, lengths, M, H, D, 2, 0);
    // 2: attention (8 q per block) -> inp = [v, C]
    attn_kernel<<<dim3(B * 64), 512, 0, stream>>>(v, lengths, own, comp, v_attn, inp);
    // 3: gate
    gemm_bias<<<dim3(8, M / 64), 256, 0, stream>>>(
        inp, gate_W, gate_b, gated, gate_W, gate_b, gated, lengths, M, 512, 512, 8, 1);
    // 4: input projections for both GRU directions in one launch
    gemm_bias<<<dim3(12, M / 64), 256, 0, stream>>>(
        gated, w_ih_f, b_ih_f, xp_f, w_ih_b, b_ih_b, xp_b, lengths, M, 384, 512, 6, 0);
    // 5: sequential GRU, one block per batch (f+b fused)
    gru_kernel<<<dim3(4), 512, 0, stream>>>(xp_f, xp_b, w_hh_f, w_hh_b, b_hh_f, b_hh_b, lengths, out);
}